// Round 19
// baseline (643.821 us; speedup 1.0000x reference)
//
#include <hip/hip_runtime.h>
#include <math.h>

#define BATCH 4
#define CIN 64
#define HW 256
#define NPIX 65536       // 256*256
#define OC 192
#define TH 294
#define NPIX_R 86436     // 294*294
#define PS2 49
#define C2N 2401
#define NWIN 36          // 6*6 windows per batch
#define WCPB 2304        // window-channels per batch (36*64)
#define KSTR 52          // LDS row stride (208 B, 16B-aligned)
#define TABN (NWIN * C2N)   // 86436 table entries
#define RS 45            // staged source patch is RS x RS (covers 49*0.8703+2)

__device__ __forceinline__ float rl_f32(float v, int lane) {
    return __uint_as_float(__builtin_amdgcn_readlane(__float_as_uint(v), lane));
}

// ---------------- K1: 1x1 conv (qkv) as LDS-tiled GEMM ----------------------
__global__ __launch_bounds__(256)
void k_qkv1x1(const float* __restrict__ x, const float* __restrict__ w,
              float* __restrict__ A) {
    __shared__ float wT[64][64];     // wT[c][o]
    __shared__ float xs[64][256];    // xs[c][px]
    x += (size_t)blockIdx.z * CIN * NPIX;
    A += (size_t)blockIdx.z * OC * NPIX;
    const int tid = threadIdx.x;
    const int pxbase = blockIdx.x * 256;
    const int ocbase = blockIdx.y * 64;

    for (int idx = tid; idx < 1024; idx += 256) {
        int o = idx >> 4, c4 = idx & 15;
        float4 v = *reinterpret_cast<const float4*>(w + (size_t)(ocbase + o) * CIN + c4 * 4);
        wT[c4 * 4 + 0][o] = v.x; wT[c4 * 4 + 1][o] = v.y;
        wT[c4 * 4 + 2][o] = v.z; wT[c4 * 4 + 3][o] = v.w;
    }
    for (int idx = tid; idx < 4096; idx += 256) {
        int c = idx >> 6, p4 = idx & 63;
        float4 v = *reinterpret_cast<const float4*>(x + (size_t)c * NPIX + pxbase + p4 * 4);
        *reinterpret_cast<float4*>(&xs[c][p4 * 4]) = v;
    }
    __syncthreads();

    const int tx = tid & 15, ty = tid >> 4;
    float acc[4][16];
    #pragma unroll
    for (int a = 0; a < 4; ++a)
        #pragma unroll
        for (int b = 0; b < 16; ++b) acc[a][b] = 0.f;

    #pragma unroll 4
    for (int k = 0; k < 64; ++k) {
        float4 wv = *reinterpret_cast<const float4*>(&wT[k][ty * 4]);
        float wr[4] = {wv.x, wv.y, wv.z, wv.w};
        float xv[16];
        #pragma unroll
        for (int i = 0; i < 4; ++i) {
            float4 v = *reinterpret_cast<const float4*>(&xs[k][tx * 4 + i * 64]);
            xv[i * 4 + 0] = v.x; xv[i * 4 + 1] = v.y;
            xv[i * 4 + 2] = v.z; xv[i * 4 + 3] = v.w;
        }
        #pragma unroll
        for (int a = 0; a < 4; ++a)
            #pragma unroll
            for (int b = 0; b < 16; ++b)
                acc[a][b] = fmaf(wr[a], xv[b], acc[a][b]);
    }

    #pragma unroll
    for (int a = 0; a < 4; ++a) {
        float* Ap = A + (size_t)(ocbase + ty * 4 + a) * NPIX + pxbase;
        #pragma unroll
        for (int i = 0; i < 4; ++i)
            *reinterpret_cast<float4*>(Ap + tx * 4 + i * 64) =
                make_float4(acc[a][i * 4 + 0], acc[a][i * 4 + 1],
                            acc[a][i * 4 + 2], acc[a][i * 4 + 3]);
    }
}

// ---------------- K2: depthwise 3x3, 8 pixels/thread ------------------------
__global__ __launch_bounds__(256)
void k_dw3x3(const float* __restrict__ A, const float* __restrict__ dwv,
             float* __restrict__ Bf) {
    A  += (size_t)blockIdx.z * OC * NPIX;
    Bf += (size_t)blockIdx.z * OC * NPIX;
    int gid = blockIdx.x * 256 + threadIdx.x;   // ch*8192 + q
    int ch = gid >> 13;                          // [0,192)
    int q  = gid & 8191;
    int y  = q >> 5;                             // [0,256)
    int x8 = (q & 31) << 3;                      // [0,256) step 8
    const float* Ap = A + (size_t)ch * NPIX;
    float wv[9];
    #pragma unroll
    for (int i = 0; i < 9; ++i) wv[i] = dwv[ch * 9 + i];
    float a[8];
    #pragma unroll
    for (int t = 0; t < 8; ++t) a[t] = 0.f;
    #pragma unroll
    for (int ky = 0; ky < 3; ++ky) {
        int yy = y + ky - 1;
        if (yy < 0 || yy >= HW) continue;
        const float* row = Ap + yy * HW;
        float4 m0 = *reinterpret_cast<const float4*>(row + x8);
        float4 m1 = *reinterpret_cast<const float4*>(row + x8 + 4);
        float lm = (x8 > 0)       ? row[x8 - 1] : 0.f;
        float rp = (x8 < HW - 8)  ? row[x8 + 8] : 0.f;
        float cv[10] = {lm, m0.x, m0.y, m0.z, m0.w, m1.x, m1.y, m1.z, m1.w, rp};
        #pragma unroll
        for (int kx = 0; kx < 3; ++kx) {
            float wk = wv[ky * 3 + kx];
            #pragma unroll
            for (int t = 0; t < 8; ++t)
                a[t] = fmaf(cv[t + kx], wk, a[t]);
        }
    }
    float* op = Bf + (size_t)ch * NPIX + y * HW + x8;
    *reinterpret_cast<float4*>(op)     = make_float4(a[0], a[1], a[2], a[3]);
    *reinterpret_cast<float4*>(op + 4) = make_float4(a[4], a[5], a[6], a[7]);
}

// ---------------- K2.5: per-window bilinear gather tables (PATCH-LOCAL) -----
// ltab: 4 offsets into the RSxRS staged patch; wtab: 4 weights.
// dtab: element -> permuted LDS slot (i*KSTR+j). otab: element -> rl*TH+cl.
__global__ __launch_bounds__(256)
void k_prep(int4* __restrict__ ltab, float4* __restrict__ wtab,
            int* __restrict__ dtab, int* __restrict__ otab) {
    const int w = blockIdx.x;                   // [0,36)
    const int xw = w / 6, yw = w - xw * 6;
    const float scale = 255.0f / 293.0f;
    const int ybase = (int)((float)(xw * PS2) * scale);
    const int xbase = (int)((float)(yw * PS2) * scale);
    for (int e = threadIdx.x; e < C2N; e += 256) {
        int rl = e / PS2, cl = e - rl * PS2;
        float sy = (float)(xw * PS2 + rl) * scale;
        float sx = (float)(yw * PS2 + cl) * scale;
        int y0 = (int)sy, x0 = (int)sx;
        float ly = sy - y0, lx = sx - x0;
        int y1 = min(y0 + 1, HW - 1), x1 = min(x0 + 1, HW - 1);
        int y0l = y0 - ybase, y1l = y1 - ybase;
        int x0l = x0 - xbase, x1l = x1 - xbase;
        ltab[w * C2N + e] = make_int4(y0l * RS + x0l, y0l * RS + x1l,
                                      y1l * RS + x0l, y1l * RS + x1l);
        wtab[w * C2N + e] = make_float4((1.f - ly) * (1.f - lx), (1.f - ly) * lx,
                                        ly * (1.f - lx),         ly * lx);
        if (w == 0) {
            int i = (cl / 7) * 7 + rl % 7;
            int j = (cl % 7) * 7 + rl / 7;
            dtab[e] = i * KSTR + j;
            otab[e] = rl * TH + cl;
        }
    }
}

// ---------------- K3: block-per-wc attention, staged-patch gather -----------
// Gather: stage the 45x45 source patch of B coalesced into LDS, then bilinear
// from LDS via patch-local tables (q -> k -> v, buffer reused). Compute: lane
// l holds K row l + V col l (pinned; may land in AGPRs), Q rows via uniform
// LDS b128, p broadcast via readlane, ssum via ones-column (lane 49).
#define PIN4(v) asm volatile("" : "+v"(v.x), "+v"(v.y), "+v"(v.z), "+v"(v.w))
#define SQ4(v) fmaf(v.x, v.x, fmaf(v.y, v.y, fmaf(v.z, v.z, v.w * v.w)))
#define DOT4(KV, OFS) { float4 q_ = *reinterpret_cast<const float4*>(qr + (OFS)); \
    dd0 = fmaf(q_.x, KV.x, dd0); dd1 = fmaf(q_.y, KV.y, dd1); \
    dd2 = fmaf(q_.z, KV.z, dd2); dd3 = fmaf(q_.w, KV.w, dd3); }
#define PV4(VV, J) { \
    o0 = fmaf(rl_f32(p, (J)+0), VV.x, o0); o1 = fmaf(rl_f32(p, (J)+1), VV.y, o1); \
    o2 = fmaf(rl_f32(p, (J)+2), VV.z, o2); o3 = fmaf(rl_f32(p, (J)+3), VV.w, o3); }
#define VC(jj) (act ? Vs[(jj) * KSTR + l] : 1.0f)

__global__ __launch_bounds__(256, 2)
void k_attn(const float* __restrict__ Bf,
            const int4* __restrict__ ltab, const float4* __restrict__ wtab,
            const int* __restrict__ dtab, const int* __restrict__ otab,
            float* __restrict__ Cf) {
    __shared__ float Qs[PS2 * KSTR];
    __shared__ float Ks[PS2 * KSTR];
    __shared__ float Vs[PS2 * KSTR];
    __shared__ float REG[RS * RS];              // staged source patch
    Bf += (size_t)blockIdx.z * OC * NPIX;
    Cf += (size_t)blockIdx.z * (size_t)CIN * NPIX_R;
    const int tid = threadIdx.x;
    const int wv = tid >> 6, lane = tid & 63;
    const int wc  = blockIdx.x;                 // [0, 2304)
    const int ch  = wc & 63;
    const int win = wc >> 6;
    const int xw  = win / 6, yw = win - xw * 6;
    const float* qb = Bf + (size_t)ch * NPIX;
    const float* kb = qb + (size_t)64  * NPIX;
    const float* vb = qb + (size_t)128 * NPIX;
    const float scale = 255.0f / 293.0f;        // align_corners=True, 256->294
    const int ybase = (int)((float)(xw * PS2) * scale);
    const int xbase = (int)((float)(yw * PS2) * scale);
    const int wbase = win * C2N;

    // phase 1: stage patch (coalesced) + bilinear from LDS, per tensor
    const float* srcs[3] = {qb, kb, vb};
    float* dsts[3] = {Qs, Ks, Vs};
    #pragma unroll
    for (int t3 = 0; t3 < 3; ++t3) {
        const float* src = srcs[t3];
        float* dst = dsts[t3];
        for (int e = tid; e < RS * RS; e += 256) {
            int r = e / RS, c2 = e - r * RS;
            REG[e] = src[(ybase + r) * HW + xbase + c2];
        }
        __syncthreads();
        for (int e = tid; e < C2N; e += 256) {
            int4   o  = ltab[wbase + e];
            float4 wt = wtab[wbase + e];
            dst[dtab[e]] = REG[o.x] * wt.x + REG[o.y] * wt.y
                         + REG[o.z] * wt.z + REG[o.w] * wt.w;
        }
        __syncthreads();
    }

    const int l = min(lane, PS2 - 1);
    const bool act = (lane < PS2);

    const float* kr0 = &Ks[l * KSTR];
    float4 k0  = *reinterpret_cast<const float4*>(kr0 + 0);
    float4 k1  = *reinterpret_cast<const float4*>(kr0 + 4);
    float4 k2  = *reinterpret_cast<const float4*>(kr0 + 8);
    float4 k3  = *reinterpret_cast<const float4*>(kr0 + 12);
    float4 k4  = *reinterpret_cast<const float4*>(kr0 + 16);
    float4 k5  = *reinterpret_cast<const float4*>(kr0 + 20);
    float4 k6  = *reinterpret_cast<const float4*>(kr0 + 24);
    float4 k7  = *reinterpret_cast<const float4*>(kr0 + 28);
    float4 k8  = *reinterpret_cast<const float4*>(kr0 + 32);
    float4 k9  = *reinterpret_cast<const float4*>(kr0 + 36);
    float4 k10 = *reinterpret_cast<const float4*>(kr0 + 40);
    float4 k11 = *reinterpret_cast<const float4*>(kr0 + 44);
    float  k48 = kr0[48];
    PIN4(k0); PIN4(k1); PIN4(k2); PIN4(k3); PIN4(k4); PIN4(k5);
    PIN4(k6); PIN4(k7); PIN4(k8); PIN4(k9); PIN4(k10); PIN4(k11);

    float kss = SQ4(k0) + SQ4(k1) + SQ4(k2) + SQ4(k3) + SQ4(k4) + SQ4(k5)
              + SQ4(k6) + SQ4(k7) + SQ4(k8) + SQ4(k9) + SQ4(k10) + SQ4(k11)
              + k48 * k48;
    const float inkl = 1.f / fmaxf(sqrtf(kss), 1e-12f);

    float4 v0  = make_float4(VC(0),  VC(1),  VC(2),  VC(3));
    float4 v1  = make_float4(VC(4),  VC(5),  VC(6),  VC(7));
    float4 v2  = make_float4(VC(8),  VC(9),  VC(10), VC(11));
    float4 v3  = make_float4(VC(12), VC(13), VC(14), VC(15));
    float4 v4  = make_float4(VC(16), VC(17), VC(18), VC(19));
    float4 v5  = make_float4(VC(20), VC(21), VC(22), VC(23));
    float4 v6  = make_float4(VC(24), VC(25), VC(26), VC(27));
    float4 v7  = make_float4(VC(28), VC(29), VC(30), VC(31));
    float4 v8  = make_float4(VC(32), VC(33), VC(34), VC(35));
    float4 v9  = make_float4(VC(36), VC(37), VC(38), VC(39));
    float4 v10 = make_float4(VC(40), VC(41), VC(42), VC(43));
    float4 v11 = make_float4(VC(44), VC(45), VC(46), VC(47));
    float  v48 = VC(48);
    PIN4(v0); PIN4(v1); PIN4(v2); PIN4(v3); PIN4(v4); PIN4(v5);
    PIN4(v6); PIN4(v7); PIN4(v8); PIN4(v9); PIN4(v10); PIN4(v11);
    asm volatile("" : "+v"(k48), "+v"(v48));

    float inql;
    {
        const float* qrl = &Qs[l * KSTR];
        float qss = 0.f;
        #pragma unroll
        for (int u = 0; u < 12; ++u) {
            float4 t = *reinterpret_cast<const float4*>(qrl + u * 4);
            qss += SQ4(t);
        }
        float q48 = qrl[48];
        qss = fmaf(q48, q48, qss);
        inql = 1.f / fmaxf(sqrtf(qss), 1e-12f);
    }
    __syncthreads();   // all norm reads of Qs complete before any row write

    for (int i = wv; i < PS2; i += 4) {
        const float inq_i = rl_f32(inql, i);
        const float* qr = &Qs[i * KSTR];        // uniform address -> broadcast
        float dd0 = 0.f, dd1 = 0.f, dd2 = 0.f, dd3 = 0.f;
        DOT4(k0, 0)   DOT4(k1, 4)   DOT4(k2, 8)   DOT4(k3, 12)
        DOT4(k4, 16)  DOT4(k5, 20)  DOT4(k6, 24)  DOT4(k7, 28)
        DOT4(k8, 32)  DOT4(k9, 36)  DOT4(k10, 40) DOT4(k11, 44)
        float dsum = (dd0 + dd1) + (dd2 + dd3);
        dsum = fmaf(qr[48], k48, dsum);
        float p = __expf(dsum * inkl * inq_i);

        float o0 = 0.f, o1 = 0.f, o2 = 0.f, o3 = 0.f;
        PV4(v0, 0)   PV4(v1, 4)   PV4(v2, 8)   PV4(v3, 12)
        PV4(v4, 16)  PV4(v5, 20)  PV4(v6, 24)  PV4(v7, 28)
        PV4(v8, 32)  PV4(v9, 36)  PV4(v10, 40) PV4(v11, 44)
        float ot = (o0 + o1) + (o2 + o3);
        ot = fmaf(rl_f32(p, 48), v48, ot);
        float ssum = rl_f32(ot, 49);            // ones-column result
        float res = ot * __builtin_amdgcn_rcpf(ssum);
        if (act) Qs[i * KSTR + lane] = res;     // row i owned by this wave
    }
    __syncthreads();

    // epilogue: table-driven inverse permutation -> spatial C (64,294,294)
    float* cb = Cf + (size_t)ch * NPIX_R + (xw * PS2) * TH + yw * PS2;
    for (int e = tid; e < C2N; e += 256)
        cb[otab[e]] = Qs[dtab[e]];
}

// ---------------- K4a: bilinear down 294->256, coalesced, 4 px/thread -------
__global__ __launch_bounds__(256)
void k_down(const float* __restrict__ Cf, float* __restrict__ D) {
    Cf += (size_t)blockIdx.z * (size_t)CIN * NPIX_R;
    D  += (size_t)blockIdx.z * (size_t)CIN * NPIX;
    int gid = blockIdx.x * 256 + threadIdx.x;   // ch*16384 + quad
    int ch = gid >> 14;                          // [0,64)
    int q  = gid & 16383;
    int y  = q >> 6;
    int x4 = (q & 63) << 2;
    const float sc = 294.0f / 256.0f;
    float sy = fmaxf((y + 0.5f) * sc - 0.5f, 0.f);
    int y0 = (int)sy;
    float ly = sy - y0;
    int y1 = min(y0 + 1, TH - 1);
    const float* r0 = Cf + (size_t)ch * NPIX_R + y0 * TH;
    const float* r1 = Cf + (size_t)ch * NPIX_R + y1 * TH;
    float res[4];
    #pragma unroll
    for (int t = 0; t < 4; ++t) {
        float sx = fmaxf((x4 + t + 0.5f) * sc - 0.5f, 0.f);
        int x0 = (int)sx;
        float lx = sx - x0;
        int x1 = min(x0 + 1, TH - 1);
        res[t] = (r0[x0] * (1.f - lx) + r0[x1] * lx) * (1.f - ly)
               + (r1[x0] * (1.f - lx) + r1[x1] * lx) * ly;
    }
    *reinterpret_cast<float4*>(D + (size_t)ch * NPIX + y * HW + x4) =
        make_float4(res[0], res[1], res[2], res[3]);
}

// ---------------- K4b: proj 1x1 conv as LDS-tiled GEMM (M=64) ---------------
__global__ __launch_bounds__(256)
void k_pmm(const float* __restrict__ D, const float* __restrict__ w,
           float* __restrict__ out) {
    __shared__ float wT[64][64];     // wT[c][o]
    __shared__ float xs[64][256];    // xs[c][px]
    D   += (size_t)blockIdx.z * CIN * NPIX;
    out += (size_t)blockIdx.z * CIN * NPIX;
    const int tid = threadIdx.x;
    const int pxbase = blockIdx.x * 256;

    for (int idx = tid; idx < 1024; idx += 256) {
        int o = idx >> 4, c4 = idx & 15;
        float4 v = *reinterpret_cast<const float4*>(w + (size_t)o * CIN + c4 * 4);
        wT[c4 * 4 + 0][o] = v.x; wT[c4 * 4 + 1][o] = v.y;
        wT[c4 * 4 + 2][o] = v.z; wT[c4 * 4 + 3][o] = v.w;
    }
    for (int idx = tid; idx < 4096; idx += 256) {
        int c = idx >> 6, p4 = idx & 63;
        float4 v = *reinterpret_cast<const float4*>(D + (size_t)c * NPIX + pxbase + p4 * 4);
        *reinterpret_cast<float4*>(&xs[c][p4 * 4]) = v;
    }
    __syncthreads();

    const int tx = tid & 15, ty = tid >> 4;
    float acc[4][16];
    #pragma unroll
    for (int a = 0; a < 4; ++a)
        #pragma unroll
        for (int b = 0; b < 16; ++b) acc[a][b] = 0.f;

    #pragma unroll 4
    for (int k = 0; k < 64; ++k) {
        float4 wv = *reinterpret_cast<const float4*>(&wT[k][ty * 4]);
        float wr[4] = {wv.x, wv.y, wv.z, wv.w};
        float xv[16];
        #pragma unroll
        for (int i = 0; i < 4; ++i) {
            float4 v = *reinterpret_cast<const float4*>(&xs[k][tx * 4 + i * 64]);
            xv[i * 4 + 0] = v.x; xv[i * 4 + 1] = v.y;
            xv[i * 4 + 2] = v.z; xv[i * 4 + 3] = v.w;
        }
        #pragma unroll
        for (int a = 0; a < 4; ++a)
            #pragma unroll
            for (int b = 0; b < 16; ++b)
                acc[a][b] = fmaf(wr[a], xv[b], acc[a][b]);
    }

    #pragma unroll
    for (int a = 0; a < 4; ++a) {
        float* op = out + (size_t)(ty * 4 + a) * NPIX + pxbase;
        #pragma unroll
        for (int i = 0; i < 4; ++i)
            *reinterpret_cast<float4*>(op + tx * 4 + i * 64) =
                make_float4(acc[a][i * 4 + 0], acc[a][i * 4 + 1],
                            acc[a][i * 4 + 2], acc[a][i * 4 + 3]);
    }
}

// ---------------- launch --------------------------------------------------
extern "C" void kernel_launch(void* const* d_in, const int* in_sizes, int n_in,
                              void* d_out, int out_size, void* d_ws, size_t ws_size,
                              hipStream_t stream) {
    const float* x   = (const float*)d_in[0];
    const float* qw  = (const float*)d_in[1];
    const float* dwv = (const float*)d_in[2];
    const float* pw  = (const float*)d_in[3];
    float* out = (float*)d_out;

    const size_t perAB = (size_t)OC * NPIX;                            // floats
    const size_t needBig = (size_t)2 * BATCH * perAB * sizeof(float);  // ~402 MB
    const size_t needMid = (size_t)2 * 2 * perAB * sizeof(float);      // ~201 MB

    int NB;
    if (ws_size >= needBig)      NB = BATCH;
    else if (ws_size >= needMid) NB = 2;
    else                         NB = 1;

    float* A = (float*)d_ws;
    float* B = A + (size_t)NB * perAB;
    float* C = A;                                       // z-stride CIN*NPIX_R
    float* D = A + (size_t)NB * CIN * NPIX_R;           // z-stride CIN*NPIX
    float* T = A + (size_t)NB * (CIN * NPIX_R + CIN * NPIX);
    int4*   ltab = (int4*)T;
    float4* wtab = (float4*)(T + (size_t)TABN * 4);
    int*    dtab = (int*)(T + (size_t)TABN * 8);
    int*    otab = dtab + C2N;

    for (int b = 0; b < BATCH; b += NB) {
        const float* xb = x + (size_t)b * CIN * NPIX;
        float* ob = out + (size_t)b * CIN * NPIX;
        hipLaunchKernelGGL(k_qkv1x1, dim3(256, 3, NB),  dim3(256), 0, stream, xb, qw, A);
        hipLaunchKernelGGL(k_dw3x3,  dim3(6144, 1, NB), dim3(256), 0, stream, A, dwv, B);
        hipLaunchKernelGGL(k_prep,   dim3(NWIN, 1, 1),  dim3(256), 0, stream,
                           ltab, wtab, dtab, otab);
        hipLaunchKernelGGL(k_attn,   dim3(WCPB, 1, NB), dim3(256), 0, stream,
                           B, ltab, wtab, dtab, otab, C);
        hipLaunchKernelGGL(k_down,   dim3(4096, 1, NB), dim3(256), 0, stream, C, D);
        hipLaunchKernelGGL(k_pmm,    dim3(256, 1, NB),  dim3(256), 0, stream, D, pw, ob);
    }
}

// Round 20
// 511.495 us; speedup vs baseline: 1.2587x; 1.2587x over previous
//
#include <hip/hip_runtime.h>
#include <math.h>

#define BATCH 4
#define CIN 64
#define HW 256
#define NPIX 65536       // 256*256
#define OC 192
#define TH 294
#define NPIX_R 86436     // 294*294
#define PS2 49
#define C2N 2401
#define NWIN 36          // 6*6 windows per batch
#define WCPB 2304        // window-channels per batch (36*64)
#define KSTR 52          // LDS row stride (208 B, 16B-aligned)
#define TABN (NWIN * C2N)   // 86436 table entries

__device__ __forceinline__ float rl_f32(float v, int lane) {
    return __uint_as_float(__builtin_amdgcn_readlane(__float_as_uint(v), lane));
}

// ---------------- K1: 1x1 conv (qkv) as LDS-tiled GEMM ----------------------
__global__ __launch_bounds__(256)
void k_qkv1x1(const float* __restrict__ x, const float* __restrict__ w,
              float* __restrict__ A) {
    __shared__ float wT[64][64];     // wT[c][o]
    __shared__ float xs[64][256];    // xs[c][px]
    x += (size_t)blockIdx.z * CIN * NPIX;
    A += (size_t)blockIdx.z * OC * NPIX;
    const int tid = threadIdx.x;
    const int pxbase = blockIdx.x * 256;
    const int ocbase = blockIdx.y * 64;

    for (int idx = tid; idx < 1024; idx += 256) {
        int o = idx >> 4, c4 = idx & 15;
        float4 v = *reinterpret_cast<const float4*>(w + (size_t)(ocbase + o) * CIN + c4 * 4);
        wT[c4 * 4 + 0][o] = v.x; wT[c4 * 4 + 1][o] = v.y;
        wT[c4 * 4 + 2][o] = v.z; wT[c4 * 4 + 3][o] = v.w;
    }
    for (int idx = tid; idx < 4096; idx += 256) {
        int c = idx >> 6, p4 = idx & 63;
        float4 v = *reinterpret_cast<const float4*>(x + (size_t)c * NPIX + pxbase + p4 * 4);
        *reinterpret_cast<float4*>(&xs[c][p4 * 4]) = v;
    }
    __syncthreads();

    const int tx = tid & 15, ty = tid >> 4;
    float acc[4][16];
    #pragma unroll
    for (int a = 0; a < 4; ++a)
        #pragma unroll
        for (int b = 0; b < 16; ++b) acc[a][b] = 0.f;

    #pragma unroll 4
    for (int k = 0; k < 64; ++k) {
        float4 wv = *reinterpret_cast<const float4*>(&wT[k][ty * 4]);
        float wr[4] = {wv.x, wv.y, wv.z, wv.w};
        float xv[16];
        #pragma unroll
        for (int i = 0; i < 4; ++i) {
            float4 v = *reinterpret_cast<const float4*>(&xs[k][tx * 4 + i * 64]);
            xv[i * 4 + 0] = v.x; xv[i * 4 + 1] = v.y;
            xv[i * 4 + 2] = v.z; xv[i * 4 + 3] = v.w;
        }
        #pragma unroll
        for (int a = 0; a < 4; ++a)
            #pragma unroll
            for (int b = 0; b < 16; ++b)
                acc[a][b] = fmaf(wr[a], xv[b], acc[a][b]);
    }

    #pragma unroll
    for (int a = 0; a < 4; ++a) {
        float* Ap = A + (size_t)(ocbase + ty * 4 + a) * NPIX + pxbase;
        #pragma unroll
        for (int i = 0; i < 4; ++i)
            *reinterpret_cast<float4*>(Ap + tx * 4 + i * 64) =
                make_float4(acc[a][i * 4 + 0], acc[a][i * 4 + 1],
                            acc[a][i * 4 + 2], acc[a][i * 4 + 3]);
    }
}

// ---------------- K2: depthwise 3x3, 8 pixels/thread ------------------------
__global__ __launch_bounds__(256)
void k_dw3x3(const float* __restrict__ A, const float* __restrict__ dwv,
             float* __restrict__ Bf) {
    A  += (size_t)blockIdx.z * OC * NPIX;
    Bf += (size_t)blockIdx.z * OC * NPIX;
    int gid = blockIdx.x * 256 + threadIdx.x;   // ch*8192 + q
    int ch = gid >> 13;                          // [0,192)
    int q  = gid & 8191;
    int y  = q >> 5;                             // [0,256)
    int x8 = (q & 31) << 3;                      // [0,256) step 8
    const float* Ap = A + (size_t)ch * NPIX;
    float wv[9];
    #pragma unroll
    for (int i = 0; i < 9; ++i) wv[i] = dwv[ch * 9 + i];
    float a[8];
    #pragma unroll
    for (int t = 0; t < 8; ++t) a[t] = 0.f;
    #pragma unroll
    for (int ky = 0; ky < 3; ++ky) {
        int yy = y + ky - 1;
        if (yy < 0 || yy >= HW) continue;
        const float* row = Ap + yy * HW;
        float4 m0 = *reinterpret_cast<const float4*>(row + x8);
        float4 m1 = *reinterpret_cast<const float4*>(row + x8 + 4);
        float lm = (x8 > 0)       ? row[x8 - 1] : 0.f;
        float rp = (x8 < HW - 8)  ? row[x8 + 8] : 0.f;
        float cv[10] = {lm, m0.x, m0.y, m0.z, m0.w, m1.x, m1.y, m1.z, m1.w, rp};
        #pragma unroll
        for (int kx = 0; kx < 3; ++kx) {
            float wk = wv[ky * 3 + kx];
            #pragma unroll
            for (int t = 0; t < 8; ++t)
                a[t] = fmaf(cv[t + kx], wk, a[t]);
        }
    }
    float* op = Bf + (size_t)ch * NPIX + y * HW + x8;
    *reinterpret_cast<float4*>(op)     = make_float4(a[0], a[1], a[2], a[3]);
    *reinterpret_cast<float4*>(op + 4) = make_float4(a[4], a[5], a[6], a[7]);
}

// ---------------- K2.5: per-window bilinear gather tables (absolute) --------
__global__ __launch_bounds__(256)
void k_prep(int4* __restrict__ itab, float4* __restrict__ wtab,
            int* __restrict__ dtab, int* __restrict__ otab) {
    const int w = blockIdx.x;                   // [0,36)
    const int xw = w / 6, yw = w - xw * 6;
    const float scale = 255.0f / 293.0f;
    for (int e = threadIdx.x; e < C2N; e += 256) {
        int rl = e / PS2, cl = e - rl * PS2;
        float sy = (float)(xw * PS2 + rl) * scale;
        float sx = (float)(yw * PS2 + cl) * scale;
        int y0 = (int)sy, x0 = (int)sx;
        float ly = sy - y0, lx = sx - x0;
        int y1 = min(y0 + 1, HW - 1), x1 = min(x0 + 1, HW - 1);
        itab[w * C2N + e] = make_int4(y0 * HW + x0, y0 * HW + x1,
                                      y1 * HW + x0, y1 * HW + x1);
        wtab[w * C2N + e] = make_float4((1.f - ly) * (1.f - lx), (1.f - ly) * lx,
                                        ly * (1.f - lx),         ly * lx);
        if (w == 0) {
            int i = (cl / 7) * 7 + rl % 7;
            int j = (cl % 7) * 7 + rl / 7;
            dtab[e] = i * KSTR + j;
            otab[e] = rl * TH + cl;
        }
    }
}

// ---------------- K3: block-per-wc attention (r17 structure) -----------------
#define PIN4(v) asm volatile("" : "+v"(v.x), "+v"(v.y), "+v"(v.z), "+v"(v.w))
#define SQ4(v) fmaf(v.x, v.x, fmaf(v.y, v.y, fmaf(v.z, v.z, v.w * v.w)))
#define DOT4(KV, OFS) { float4 q_ = *reinterpret_cast<const float4*>(qr + (OFS)); \
    dd0 = fmaf(q_.x, KV.x, dd0); dd1 = fmaf(q_.y, KV.y, dd1); \
    dd2 = fmaf(q_.z, KV.z, dd2); dd3 = fmaf(q_.w, KV.w, dd3); }
#define PV4(VV, J) { \
    o0 = fmaf(rl_f32(p, (J)+0), VV.x, o0); o1 = fmaf(rl_f32(p, (J)+1), VV.y, o1); \
    o2 = fmaf(rl_f32(p, (J)+2), VV.z, o2); o3 = fmaf(rl_f32(p, (J)+3), VV.w, o3); }
#define VC(jj) (act ? Vs[(jj) * KSTR + l] : 1.0f)
#define GBODY(E) { \
    int4   o_  = itab[wbase + (E)]; \
    float4 wt_ = wtab[wbase + (E)]; \
    int    d_  = dtab[(E)]; \
    Qs[d_] = qb[o_.x] * wt_.x + qb[o_.y] * wt_.y + qb[o_.z] * wt_.z + qb[o_.w] * wt_.w; \
    Ks[d_] = kb[o_.x] * wt_.x + kb[o_.y] * wt_.y + kb[o_.z] * wt_.z + kb[o_.w] * wt_.w; \
    Vs[d_] = vb[o_.x] * wt_.x + vb[o_.y] * wt_.y + vb[o_.z] * wt_.z + vb[o_.w] * wt_.w; }

__global__ __launch_bounds__(256, 2)
void k_attn(const float* __restrict__ Bf,
            const int4* __restrict__ itab, const float4* __restrict__ wtab,
            const int* __restrict__ dtab, const int* __restrict__ otab,
            float* __restrict__ Cf) {
    __shared__ float Qs[PS2 * KSTR];
    __shared__ float Ks[PS2 * KSTR];
    __shared__ float Vs[PS2 * KSTR];
    Bf += (size_t)blockIdx.z * OC * NPIX;
    Cf += (size_t)blockIdx.z * (size_t)CIN * NPIX_R;
    const int tid = threadIdx.x;
    const int wv = tid >> 6, lane = tid & 63;
    const int wc  = blockIdx.x;                 // [0, 2304)
    const int ch  = wc & 63;
    const int win = wc >> 6;
    const int xw  = win / 6, yw = win - xw * 6;
    const float* qb = Bf + (size_t)ch * NPIX;
    const float* kb = qb + (size_t)64  * NPIX;
    const float* vb = qb + (size_t)128 * NPIX;
    const int wbase = win * C2N;

    // phase 1: table-driven gather, unrolled for memory-level parallelism
    #pragma unroll 3
    for (int it = 0; it < 9; ++it) {
        int e = tid + it * 256;                 // covers [0, 2304)
        GBODY(e)
    }
    if (tid < C2N - 2304) {                     // 97-element tail
        GBODY(2304 + tid)
    }
    __syncthreads();

    const int l = min(lane, PS2 - 1);
    const bool act = (lane < PS2);

    const float* kr0 = &Ks[l * KSTR];
    float4 k0  = *reinterpret_cast<const float4*>(kr0 + 0);
    float4 k1  = *reinterpret_cast<const float4*>(kr0 + 4);
    float4 k2  = *reinterpret_cast<const float4*>(kr0 + 8);
    float4 k3  = *reinterpret_cast<const float4*>(kr0 + 12);
    float4 k4  = *reinterpret_cast<const float4*>(kr0 + 16);
    float4 k5  = *reinterpret_cast<const float4*>(kr0 + 20);
    float4 k6  = *reinterpret_cast<const float4*>(kr0 + 24);
    float4 k7  = *reinterpret_cast<const float4*>(kr0 + 28);
    float4 k8  = *reinterpret_cast<const float4*>(kr0 + 32);
    float4 k9  = *reinterpret_cast<const float4*>(kr0 + 36);
    float4 k10 = *reinterpret_cast<const float4*>(kr0 + 40);
    float4 k11 = *reinterpret_cast<const float4*>(kr0 + 44);
    float  k48 = kr0[48];
    PIN4(k0); PIN4(k1); PIN4(k2); PIN4(k3); PIN4(k4); PIN4(k5);
    PIN4(k6); PIN4(k7); PIN4(k8); PIN4(k9); PIN4(k10); PIN4(k11);

    float kss = SQ4(k0) + SQ4(k1) + SQ4(k2) + SQ4(k3) + SQ4(k4) + SQ4(k5)
              + SQ4(k6) + SQ4(k7) + SQ4(k8) + SQ4(k9) + SQ4(k10) + SQ4(k11)
              + k48 * k48;
    const float inkl = 1.f / fmaxf(sqrtf(kss), 1e-12f);

    float4 v0  = make_float4(VC(0),  VC(1),  VC(2),  VC(3));
    float4 v1  = make_float4(VC(4),  VC(5),  VC(6),  VC(7));
    float4 v2  = make_float4(VC(8),  VC(9),  VC(10), VC(11));
    float4 v3  = make_float4(VC(12), VC(13), VC(14), VC(15));
    float4 v4  = make_float4(VC(16), VC(17), VC(18), VC(19));
    float4 v5  = make_float4(VC(20), VC(21), VC(22), VC(23));
    float4 v6  = make_float4(VC(24), VC(25), VC(26), VC(27));
    float4 v7  = make_float4(VC(28), VC(29), VC(30), VC(31));
    float4 v8  = make_float4(VC(32), VC(33), VC(34), VC(35));
    float4 v9  = make_float4(VC(36), VC(37), VC(38), VC(39));
    float4 v10 = make_float4(VC(40), VC(41), VC(42), VC(43));
    float4 v11 = make_float4(VC(44), VC(45), VC(46), VC(47));
    float  v48 = VC(48);
    PIN4(v0); PIN4(v1); PIN4(v2); PIN4(v3); PIN4(v4); PIN4(v5);
    PIN4(v6); PIN4(v7); PIN4(v8); PIN4(v9); PIN4(v10); PIN4(v11);
    asm volatile("" : "+v"(k48), "+v"(v48));

    float inql;
    {
        const float* qrl = &Qs[l * KSTR];
        float qss = 0.f;
        #pragma unroll
        for (int u = 0; u < 12; ++u) {
            float4 t = *reinterpret_cast<const float4*>(qrl + u * 4);
            qss += SQ4(t);
        }
        float q48 = qrl[48];
        qss = fmaf(q48, q48, qss);
        inql = 1.f / fmaxf(sqrtf(qss), 1e-12f);
    }
    __syncthreads();   // all norm reads of Qs complete before any row write

    for (int i = wv; i < PS2; i += 4) {
        const float inq_i = rl_f32(inql, i);
        const float* qr = &Qs[i * KSTR];        // uniform address -> broadcast
        float dd0 = 0.f, dd1 = 0.f, dd2 = 0.f, dd3 = 0.f;
        DOT4(k0, 0)   DOT4(k1, 4)   DOT4(k2, 8)   DOT4(k3, 12)
        DOT4(k4, 16)  DOT4(k5, 20)  DOT4(k6, 24)  DOT4(k7, 28)
        DOT4(k8, 32)  DOT4(k9, 36)  DOT4(k10, 40) DOT4(k11, 44)
        float dsum = (dd0 + dd1) + (dd2 + dd3);
        dsum = fmaf(qr[48], k48, dsum);
        float p = __expf(dsum * inkl * inq_i);

        float o0 = 0.f, o1 = 0.f, o2 = 0.f, o3 = 0.f;
        PV4(v0, 0)   PV4(v1, 4)   PV4(v2, 8)   PV4(v3, 12)
        PV4(v4, 16)  PV4(v5, 20)  PV4(v6, 24)  PV4(v7, 28)
        PV4(v8, 32)  PV4(v9, 36)  PV4(v10, 40) PV4(v11, 44)
        float ot = (o0 + o1) + (o2 + o3);
        ot = fmaf(rl_f32(p, 48), v48, ot);
        float ssum = rl_f32(ot, 49);            // ones-column result
        float res = ot * __builtin_amdgcn_rcpf(ssum);
        if (act) Qs[i * KSTR + lane] = res;     // row i owned by this wave
    }
    __syncthreads();

    // epilogue: table-driven inverse permutation -> spatial C (64,294,294)
    float* cb = Cf + (size_t)ch * NPIX_R + (xw * PS2) * TH + yw * PS2;
    for (int e = tid; e < C2N; e += 256)
        cb[otab[e]] = Qs[dtab[e]];
}

// ------- K4: fused bilinear-down (294->256) + proj GEMM, one row per block --
__global__ __launch_bounds__(256)
void k_downpmm(const float* __restrict__ Cf, const float* __restrict__ w,
               float* __restrict__ out) {
    __shared__ float wT[64][64];     // wT[c][o]
    __shared__ float xs[64][256];    // downsampled row, all 64 channels
    Cf  += (size_t)blockIdx.z * (size_t)CIN * NPIX_R;
    out += (size_t)blockIdx.z * CIN * NPIX;
    const int tid = threadIdx.x;
    const int y = blockIdx.x;                   // output row [0,256)
    const float sc = 294.0f / 256.0f;
    float sy = fmaxf((y + 0.5f) * sc - 0.5f, 0.f);
    int y0 = (int)sy;
    float ly = sy - y0;
    int y1 = min(y0 + 1, TH - 1);
    float sx = fmaxf((tid + 0.5f) * sc - 0.5f, 0.f);
    int x0 = (int)sx;
    float lx = sx - x0;
    int x1 = min(x0 + 1, TH - 1);
    const float w00 = (1.f - ly) * (1.f - lx), w01 = (1.f - ly) * lx;
    const float w10 = ly * (1.f - lx),         w11 = ly * lx;

    for (int idx = tid; idx < 1024; idx += 256) {
        int o = idx >> 4, c4 = idx & 15;
        float4 v = *reinterpret_cast<const float4*>(w + (size_t)o * CIN + c4 * 4);
        wT[c4 * 4 + 0][o] = v.x; wT[c4 * 4 + 1][o] = v.y;
        wT[c4 * 4 + 2][o] = v.z; wT[c4 * 4 + 3][o] = v.w;
    }
    #pragma unroll 4
    for (int ch = 0; ch < 64; ++ch) {
        const float* r0 = Cf + (size_t)ch * NPIX_R + y0 * TH;
        const float* r1 = Cf + (size_t)ch * NPIX_R + y1 * TH;
        xs[ch][tid] = r0[x0] * w00 + r0[x1] * w01 + r1[x0] * w10 + r1[x1] * w11;
    }
    __syncthreads();

    const int tx = tid & 15, ty = tid >> 4;
    float acc[4][16];
    #pragma unroll
    for (int a = 0; a < 4; ++a)
        #pragma unroll
        for (int b = 0; b < 16; ++b) acc[a][b] = 0.f;

    #pragma unroll 4
    for (int k = 0; k < 64; ++k) {
        float4 wv = *reinterpret_cast<const float4*>(&wT[k][ty * 4]);
        float wr[4] = {wv.x, wv.y, wv.z, wv.w};
        float xv[16];
        #pragma unroll
        for (int i = 0; i < 4; ++i) {
            float4 v = *reinterpret_cast<const float4*>(&xs[k][tx * 4 + i * 64]);
            xv[i * 4 + 0] = v.x; xv[i * 4 + 1] = v.y;
            xv[i * 4 + 2] = v.z; xv[i * 4 + 3] = v.w;
        }
        #pragma unroll
        for (int a = 0; a < 4; ++a)
            #pragma unroll
            for (int b = 0; b < 16; ++b)
                acc[a][b] = fmaf(wr[a], xv[b], acc[a][b]);
    }

    #pragma unroll
    for (int a = 0; a < 4; ++a) {
        float* op = out + (size_t)(ty * 4 + a) * NPIX + y * HW;
        #pragma unroll
        for (int i = 0; i < 4; ++i)
            *reinterpret_cast<float4*>(op + tx * 4 + i * 64) =
                make_float4(acc[a][i * 4 + 0], acc[a][i * 4 + 1],
                            acc[a][i * 4 + 2], acc[a][i * 4 + 3]);
    }
}

// ---------------- launch --------------------------------------------------
// ws layout per NB batches in flight (floats):
//   [0, NB*perAB)            A region; after A dies hosts:
//       C  at 0              (z-stride CIN*NPIX_R, NB*5.53M)
//       tables after C       (itab/wtab/dtab/otab, ~0.70M)   [rebuilt per iter]
//   [NB*perAB, 2*NB*perAB)   B region (qkv post-dw)
extern "C" void kernel_launch(void* const* d_in, const int* in_sizes, int n_in,
                              void* d_out, int out_size, void* d_ws, size_t ws_size,
                              hipStream_t stream) {
    const float* x   = (const float*)d_in[0];
    const float* qw  = (const float*)d_in[1];
    const float* dwv = (const float*)d_in[2];
    const float* pw  = (const float*)d_in[3];
    float* out = (float*)d_out;

    const size_t perAB = (size_t)OC * NPIX;                            // floats
    const size_t needBig = (size_t)2 * BATCH * perAB * sizeof(float);  // ~402 MB
    const size_t needMid = (size_t)2 * 2 * perAB * sizeof(float);      // ~201 MB

    int NB;
    if (ws_size >= needBig)      NB = BATCH;
    else if (ws_size >= needMid) NB = 2;
    else                         NB = 1;

    float* A = (float*)d_ws;
    float* B = A + (size_t)NB * perAB;
    float* C = A;                                       // z-stride CIN*NPIX_R
    float* T = A + (size_t)NB * CIN * NPIX_R;
    int4*   itab = (int4*)T;
    float4* wtab = (float4*)(T + (size_t)TABN * 4);
    int*    dtab = (int*)(T + (size_t)TABN * 8);
    int*    otab = dtab + C2N;

    for (int b = 0; b < BATCH; b += NB) {
        const float* xb = x + (size_t)b * CIN * NPIX;
        float* ob = out + (size_t)b * CIN * NPIX;
        hipLaunchKernelGGL(k_qkv1x1,  dim3(256, 3, NB),  dim3(256), 0, stream, xb, qw, A);
        hipLaunchKernelGGL(k_dw3x3,   dim3(6144, 1, NB), dim3(256), 0, stream, A, dwv, B);
        hipLaunchKernelGGL(k_prep,    dim3(NWIN, 1, 1),  dim3(256), 0, stream,
                           itab, wtab, dtab, otab);
        hipLaunchKernelGGL(k_attn,    dim3(WCPB, 1, NB), dim3(256), 0, stream,
                           B, itab, wtab, dtab, otab, C);
        hipLaunchKernelGGL(k_downpmm, dim3(256, 1, NB),  dim3(256), 0, stream, C, pw, ob);
    }
}